// Round 1
// baseline (391.288 us; speedup 1.0000x reference)
//
#include <hip/hip_runtime.h>

// FP32->FP16 bit-sliced converter.
// Input : (2048*1024) elements x 32 float bits (0.0/1.0), MSB-first:
//         [sign, exp[7:0] msb-first, mant[22:0] msb-first]
// Output: (2048*1024) elements x 16 float bits, MSB-first:
//         [sign, exp5 msb-first, mant10 msb-first]
// Exactly replicates the reference mux chain:
//   result; overflow(E>142)->inf; underflow(E<113)->all-zero; is_inf->inf; is_nan->s|0x7E00

__global__ __launch_bounds__(256) void fp32_to_fp16_bits_kernel(
    const float* __restrict__ in, float* __restrict__ out, int n_elems)
{
    int e = blockIdx.x * blockDim.x + threadIdx.x;
    if (e >= n_elems) return;

    const float4* in4 = reinterpret_cast<const float4*>(in) + (size_t)e * 8;
    uint32_t bits = 0u;
#pragma unroll
    for (int k = 0; k < 8; ++k) {
        float4 v = in4[k];
        uint32_t b0 = (v.x != 0.0f) ? 1u : 0u;
        uint32_t b1 = (v.y != 0.0f) ? 1u : 0u;
        uint32_t b2 = (v.z != 0.0f) ? 1u : 0u;
        uint32_t b3 = (v.w != 0.0f) ? 1u : 0u;
        int sh = 31 - 4 * k;
        bits |= (b0 << sh) | (b1 << (sh - 1)) | (b2 << (sh - 2)) | (b3 << (sh - 3));
    }

    uint32_t s = bits >> 31;                  // sign
    uint32_t E = (bits >> 23) & 0xFFu;        // 8-bit exponent
    uint32_t M = bits & 0x7FFFFFu;            // 23-bit mantissa

    // Round-to-nearest-even on top 10 mantissa bits
    uint32_t mant10   = M >> 13;
    uint32_t L        = mant10 & 1u;
    uint32_t R        = (M >> 12) & 1u;
    uint32_t S        = ((M & 0xFFFu) != 0u) ? 1u : 0u;
    uint32_t round_up = R & (L | S);

    uint32_t mr       = mant10 + round_up;    // 11-bit result
    uint32_t carry    = mr >> 10;
    uint32_t mant_out = mr & 0x3FFu;

    uint32_t exp5 = (E - 112u + carry) & 0x1Fu;  // matches 8-bit sub -> low5, +carry mod 32

    uint32_t h = (s << 15) | (exp5 << 10) | mant_out;

    // Mux chain, in reference order (later assignments override earlier):
    bool e_all = (E == 0xFFu);
    bool m_any = (M != 0u);
    if (E > 142u)        h = (s << 15) | 0x7C00u;   // overflow  -> inf
    if (E < 113u)        h = 0u;                    // underflow -> +0 (sign cleared too)
    if (e_all && !m_any) h = (s << 15) | 0x7C00u;   // inf
    if (e_all &&  m_any) h = (s << 15) | 0x7E00u;   // nan (qNaN, mant msb set)

    // Unpack 16 bits, MSB-first, as floats
    float4* o4 = reinterpret_cast<float4*>(out) + (size_t)e * 4;
#pragma unroll
    for (int k = 0; k < 4; ++k) {
        int sh = 15 - 4 * k;
        float4 v;
        v.x = (float)((h >> sh) & 1u);
        v.y = (float)((h >> (sh - 1)) & 1u);
        v.z = (float)((h >> (sh - 2)) & 1u);
        v.w = (float)((h >> (sh - 3)) & 1u);
        o4[k] = v;
    }
}

extern "C" void kernel_launch(void* const* d_in, const int* in_sizes, int n_in,
                              void* d_out, int out_size, void* d_ws, size_t ws_size,
                              hipStream_t stream) {
    const float* in = (const float*)d_in[0];
    float* out = (float*)d_out;
    int n_elems = in_sizes[0] / 32;   // 2048*1024 = 2,097,152
    int block = 256;
    int grid = (n_elems + block - 1) / block;
    fp32_to_fp16_bits_kernel<<<grid, block, 0, stream>>>(in, out, n_elems);
}

// Round 2
// 386.162 us; speedup vs baseline: 1.0133x; 1.0133x over previous
//
#include <hip/hip_runtime.h>

// FP32->FP16 bit-sliced converter, fully coalesced via ballot/shfl transpose.
// Wave of 64 lanes handles 64 consecutive elements (each element = 32 input
// bit-floats, 16 output bit-floats).
//
// Load: 8 coalesced float4 rows per wave (1 KiB/instr). Row j's 4 ballots
// (one per float4 component) hold the bits of elements [j*8, j*8+8):
//   ballot_c bit l = float (j*256 + 4l + c) within the wave's 2048-float region.
// Lane `rel` owns element rel: captures row j = rel>>3's masks, takes byte
// (rel&7) of each, spreads bit k -> 4k, bit-reverses (-> 31-4k), shifts by c
// -> packed MSB-first uint32 (bit 31-t = float t).
//
// Store: 4 coalesced float4 rows; lane l's slot k*64+l covers element
// 16k + (l>>2), nibble (l&3) -> __shfl the 16-bit result from the owning lane.

__device__ __forceinline__ uint32_t spread4(uint32_t x) {
    // 8-bit input, bit k -> bit 4k
    x &= 0xFFu;
    x = (x | (x << 12)) & 0x000F000Fu;
    x = (x | (x << 6))  & 0x03030303u;
    x = (x | (x << 3))  & 0x11111111u;
    return x;
}

__global__ __launch_bounds__(256) void fp32_to_fp16_bits_kernel(
    const float* __restrict__ in, float* __restrict__ out, int n_elems)
{
    int tid  = blockIdx.x * blockDim.x + threadIdx.x;
    int lane = threadIdx.x & 63;
    long elemBase = (long)(tid >> 6) * 64;
    if (elemBase >= n_elems) return;   // n_elems is a multiple of 64; whole waves only

    const float4* in4 = reinterpret_cast<const float4*>(in) + elemBase * 8;

    // ---- coalesced loads: 8 x 1KiB rows ----
    float4 v[8];
#pragma unroll
    for (int j = 0; j < 8; ++j) v[j] = in4[j * 64 + lane];

    // ---- ballot transpose: lane `lane` captures its row's 4 masks ----
    unsigned long long z0 = 0, z1 = 0, z2 = 0, z3 = 0;
#pragma unroll
    for (int j = 0; j < 8; ++j) {
        unsigned long long b0 = __ballot(v[j].x != 0.0f);
        unsigned long long b1 = __ballot(v[j].y != 0.0f);
        unsigned long long b2 = __ballot(v[j].z != 0.0f);
        unsigned long long b3 = __ballot(v[j].w != 0.0f);
        if ((lane >> 3) == j) { z0 = b0; z1 = b1; z2 = b2; z3 = b3; }
    }

    int shb = (lane & 7) << 3;
    uint32_t B0 = (uint32_t)(z0 >> shb) & 0xFFu;
    uint32_t B1 = (uint32_t)(z1 >> shb) & 0xFFu;
    uint32_t B2 = (uint32_t)(z2 >> shb) & 0xFFu;
    uint32_t B3 = (uint32_t)(z3 >> shb) & 0xFFu;

    uint32_t bits = (__brev(spread4(B0))     )
                  | (__brev(spread4(B1)) >> 1)
                  | (__brev(spread4(B2)) >> 2)
                  | (__brev(spread4(B3)) >> 3);

    // ---- FP32 -> FP16 round-to-nearest-even (verified bit-exact vs ref) ----
    uint32_t s = bits >> 31;
    uint32_t E = (bits >> 23) & 0xFFu;
    uint32_t M = bits & 0x7FFFFFu;

    uint32_t mant10   = M >> 13;
    uint32_t L        = mant10 & 1u;
    uint32_t R        = (M >> 12) & 1u;
    uint32_t S        = ((M & 0xFFFu) != 0u) ? 1u : 0u;
    uint32_t round_up = R & (L | S);

    uint32_t mr       = mant10 + round_up;
    uint32_t carry    = mr >> 10;
    uint32_t mant_out = mr & 0x3FFu;
    uint32_t exp5     = (E - 112u + carry) & 0x1Fu;

    uint32_t h = (s << 15) | (exp5 << 10) | mant_out;

    bool e_all = (E == 0xFFu);
    bool m_any = (M != 0u);
    if (E > 142u)        h = (s << 15) | 0x7C00u;   // overflow  -> inf
    if (E < 113u)        h = 0u;                    // underflow -> +0 (sign cleared)
    if (e_all && !m_any) h = (s << 15) | 0x7C00u;   // inf
    if (e_all &&  m_any) h = (s << 15) | 0x7E00u;   // nan

    // ---- coalesced stores: 4 x 1KiB rows, shfl-gather the owning lane's h ----
    float4* o4 = reinterpret_cast<float4*>(out) + elemBase * 4;
#pragma unroll
    for (int k = 0; k < 4; ++k) {
        int src = 16 * k + (lane >> 2);
        uint32_t hh = (uint32_t)__shfl((int)h, src, 64);
        int base = 15 - 4 * (lane & 3);
        float4 o;
        o.x = (float)((hh >> base)       & 1u);
        o.y = (float)((hh >> (base - 1)) & 1u);
        o.z = (float)((hh >> (base - 2)) & 1u);
        o.w = (float)((hh >> (base - 3)) & 1u);
        o4[k * 64 + lane] = o;
    }
}

extern "C" void kernel_launch(void* const* d_in, const int* in_sizes, int n_in,
                              void* d_out, int out_size, void* d_ws, size_t ws_size,
                              hipStream_t stream) {
    const float* in = (const float*)d_in[0];
    float* out = (float*)d_out;
    int n_elems = in_sizes[0] / 32;   // 2048*1024 = 2,097,152 (multiple of 64)
    int block = 256;
    int grid = (n_elems + block - 1) / block;
    fp32_to_fp16_bits_kernel<<<grid, block, 0, stream>>>(in, out, n_elems);
}